// Round 21
// baseline (58.772 us; speedup 1.0000x reference)
//
#include <hip/hip_runtime.h>
#include <hip/hip_bf16.h>

#define N 8192
#define D 256
#define NSLICE 16
#define BM 256                          // rows per block (4 waves x 64 rows)
#define TROWS 4                         // row-tiles of 16 per wave
#define COLS_PER_SLICE (N / NSLICE)     // 512
#define NSTRIP (COLS_PER_SLICE / 16)    // 32 strips of 16 cols
#define NRB (N / BM)                    // 32 row blocks

#define CSHIFT 160.0f                   // fixed base-2 LSE shift
#define K2LOG2E 2.885390082f            // (1/T) * log2(e) = 2 * 1.44269504
#define LN2F 0.6931471805599453f

typedef __attribute__((ext_vector_type(4))) float f32x4;

__device__ inline float fast_exp2(float x) { return __builtin_amdgcn_exp2f(x); }
__device__ inline float fast_log2(float x) { return __builtin_amdgcn_logf(x); }

// pack 4 fp32 -> 4 fp8 e4m3 bytes (OCP on gfx950)
__device__ inline unsigned int pack_fp8x4(float a, float b, float c, float d) {
    unsigned int p = __builtin_amdgcn_cvt_pk_fp8_f32(a, b, 0, 0);    // bytes 0-1
    p = __builtin_amdgcn_cvt_pk_fp8_f32(c, d, (int)p, 1);            // bytes 2-3
    return p;
}

// ---------------- kernel 0: fp32 -> fp8 (fragment order) + hist + colsum zero --------
// y==0: F -> Fb8 fragment-order; block x==0 also does the 14-bin ballot hist.
// y==1: Imp -> Ib8 fragment-order; blocks x<32 also zero colsum.
// (diag dot now captured inside tile_pass from the pre-mask MFMA accumulator)
__global__ void convert_fp8(const float* __restrict__ F, const float* __restrict__ Imp,
                            unsigned int* __restrict__ Fb8, unsigned int* __restrict__ Ib8,
                            const int* __restrict__ labels, int* __restrict__ counts,
                            float* __restrict__ colsum) {
    const int tid = threadIdx.x;
    const int i = blockIdx.x * blockDim.x + tid;  // 8 bytes per thread
    const float* src = (blockIdx.y == 0) ? F : Imp;
    unsigned int* dst = (blockIdx.y == 0) ? Fb8 : Ib8;
    const int l = i & 63;
    const int ks = (i >> 6) & 7;
    const int g = i >> 9;
    const int row = g * 16 + (l & 15);
    const int k0 = ks * 32 + (l >> 4) * 8;
    const float* p = src + (size_t)row * D + k0;
    const float4 v0 = *reinterpret_cast<const float4*>(p);
    const float4 v1 = *reinterpret_cast<const float4*>(p + 4);
    dst[i * 2] = pack_fp8x4(v0.x, v0.y, v0.z, v0.w);
    dst[i * 2 + 1] = pack_fp8x4(v1.x, v1.y, v1.z, v1.w);

    if (blockIdx.y == 1 && blockIdx.x < 32)
        colsum[blockIdx.x * 256 + tid] = 0.0f;

    if (blockIdx.y == 0 && blockIdx.x == 0) {  // ballot histogram, one block
        const int lane = tid & 63;
        const int wave = tid >> 6;
        int c = 0;
        for (int j = wave * 2048 + lane; j < wave * 2048 + 2048; j += 64) {
            const int lab = labels[j];
#pragma unroll
            for (int b = 0; b < 14; ++b) {
                unsigned long long m = __ballot(lab == b);
                if (lane == b) c += __popcll(m);
            }
        }
        __shared__ int wc[4][16];
        if (lane < 16) wc[wave][lane] = (lane < 14) ? c : 0;
        __syncthreads();
        if (tid < 16)
            counts[tid] = wc[0][tid] + wc[1][tid] + wc[2][tid] + wc[3][tid];
    }
}

// ---------------- kernel 1: free-running fp8 kernel, deferred-epilogue pipeline --------
// r20 core unchanged (no B LDS staging, no main-loop barriers, two acc sets,
// launch_bounds(256,2) — tighter caps spill: r5/r10/r16; grid 512 = 2 blk/CU).
// NEW: diagonal dot captured from the pre-mask accumulator (grow==mycol is a
// subset of the label-equal masked set) -> convert's 32MB fp32 diag pass gone.
// blockIdx.x: row block (256 rows), blockIdx.y: column slice (512 cols).
__launch_bounds__(256, 2)
__global__ void tile_pass(const unsigned char* __restrict__ Fb8,
                          const unsigned char* __restrict__ Ib8,
                          const int* __restrict__ labels,
                          float* __restrict__ partials_row,    // [N][NSLICE]
                          float* __restrict__ colsum,          // [N], atomic
                          float* __restrict__ diagArr) {       // [N]
    __shared__ float colacc[4][COLS_PER_SLICE];   // 8KB, per-wave private
    __shared__ int labs[COLS_PER_SLICE];          // 2KB

    const int tid = threadIdx.x;
    const int lane = tid & 63;
    const int wave = tid >> 6;
    const int rb = blockIdx.x;
    const int row0 = rb * BM + wave * (16 * TROWS);
    const int rg0 = row0 >> 4;                    // A row-group index
    const int c0 = blockIdx.y * COLS_PER_SLICE;
    const int cg0 = c0 >> 4;                      // B col-group index
    const int lrow = lane & 15;
    const int kgrp = lane >> 4;

    for (int i = tid; i < COLS_PER_SLICE; i += 256) {
        labs[i] = labels[c0 + i];
        colacc[0][i] = 0.f; colacc[1][i] = 0.f; colacc[2][i] = 0.f; colacc[3][i] = 0.f;
    }

    // A fragments (fragment-ordered global): coalesced b64 per (t,ks)
    long afrag[TROWS][8];
#pragma unroll
    for (int t = 0; t < TROWS; ++t)
#pragma unroll
        for (int ks = 0; ks < 8; ++ks)
            afrag[t][ks] = *reinterpret_cast<const long*>(
                Fb8 + (size_t)(rg0 + t) * 4096 + ks * 512 + lane * 8);

    int labr[TROWS][4];
#pragma unroll
    for (int t = 0; t < TROWS; ++t) {
        const int base = row0 + t * 16 + kgrp * 4;
#pragma unroll
        for (int r = 0; r < 4; ++r) labr[t][r] = labels[base + r];
    }

    float s[TROWS][4];
#pragma unroll
    for (int t = 0; t < TROWS; ++t)
#pragma unroll
        for (int r = 0; r < 4; ++r) s[t][r] = 0.0f;

    __syncthreads();  // labs/colacc ready — the ONLY pre-epilogue barrier

#define LOADB(buf, st)                                                          \
    {                                                                           \
        const unsigned char* sb = Ib8 + (size_t)(cg0 + (st)) * 4096 + lane * 8; \
        _Pragma("unroll")                                                       \
        for (int ks = 0; ks < 8; ++ks)                                          \
            buf[ks] = *reinterpret_cast<const long*>(sb + ks * 512);            \
    }

#define MFMA_STRIP(acc, buf)                                                    \
    {                                                                           \
        _Pragma("unroll")                                                       \
        for (int t = 0; t < TROWS; ++t) acc[t] = f32x4{0.f, 0.f, 0.f, 0.f};     \
        _Pragma("unroll")                                                       \
        for (int ks = 0; ks < 8; ++ks)                                          \
            _Pragma("unroll")                                                   \
            for (int t = 0; t < TROWS; ++t)                                     \
                acc[t] = __builtin_amdgcn_mfma_f32_16x16x32_fp8_fp8(            \
                    afrag[t][ks], buf[ks], acc[t], 0, 0, 0);                    \
    }

#define EPI(acc, st)                                                            \
    {                                                                           \
        const int labc = labs[(st) * 16 + lrow];                                \
        const int mycol = c0 + (st) * 16 + lrow;                                \
        float colpart = 0.0f;                                                   \
        _Pragma("unroll")                                                       \
        for (int t = 0; t < TROWS; ++t) {                                       \
            _Pragma("unroll")                                                   \
            for (int r = 0; r < 4; ++r) {                                       \
                const int grow = row0 + t * 16 + kgrp * 4 + r;                  \
                const bool msk = (labr[t][r] == labc);                          \
                if (msk && grow == mycol) diagArr[grow] = acc[t][r];            \
                float arg = __builtin_fmaf(acc[t][r], K2LOG2E, -CSHIFT);        \
                arg = msk ? -1000.0f : arg;                                     \
                float e = fast_exp2(arg);                                       \
                s[t][r] += e;                                                   \
                colpart += e;                                                   \
            }                                                                   \
        }                                                                       \
        colpart += __shfl_xor(colpart, 16, 64);                                 \
        colpart += __shfl_xor(colpart, 32, 64);                                 \
        if (kgrp == 0) colacc[wave][(st) * 16 + lrow] += colpart;               \
    }

    long b0[8], b1[8];
    f32x4 acc0[TROWS], acc1[TROWS];

    LOADB(b0, 0);
    LOADB(b1, 1);
    MFMA_STRIP(acc0, b0);

#pragma unroll 1
    for (int st = 0; st < NSTRIP; st += 2) {
        if (st + 2 < NSTRIP) LOADB(b0, st + 2);
        MFMA_STRIP(acc1, b1);
        EPI(acc0, st);
        if (st + 3 < NSTRIP) LOADB(b1, st + 3);
        if (st + 2 < NSTRIP) MFMA_STRIP(acc0, b0);
        EPI(acc1, st + 1);
    }
#undef LOADB
#undef MFMA_STRIP
#undef EPI

    // row partials: sum the 16 lrow-lanes (disjoint column subsets)
#pragma unroll
    for (int off = 1; off < 16; off <<= 1) {
#pragma unroll
        for (int t = 0; t < TROWS; ++t)
#pragma unroll
            for (int r = 0; r < 4; ++r)
                s[t][r] += __shfl_xor(s[t][r], off, 64);
    }
    if (lrow == 0) {
#pragma unroll
        for (int t = 0; t < TROWS; ++t)
#pragma unroll
            for (int r = 0; r < 4; ++r) {
                const int grow = row0 + t * 16 + kgrp * 4 + r;
                partials_row[(size_t)grow * NSLICE + blockIdx.y] = s[t][r];
            }
    }

    __syncthreads();  // all colacc writes visible
    for (int i = tid; i < COLS_PER_SLICE; i += 256) {
        float v = colacc[0][i] + colacc[1][i] + colacc[2][i] + colacc[3][i];
        atomicAdd(&colsum[c0 + i], v);  // 32 blocks per address, pre-zeroed
    }
}

// exact lse over { S*2^CSHIFT (bulk), cnt*exp(0), exp(diag) }
__device__ inline float final_lse(float S, float cntlog, float diag) {
    float l1 = (S > 0.0f) ? (CSHIFT + fast_log2(S)) * LN2F : -INFINITY;
    float M = fmaxf(fmaxf(l1, cntlog), diag);  // M finite: diag always finite
    return M + __logf(__expf(l1 - M) + __expf(cntlog - M) + __expf(diag - M));
}

// ---------------- kernel 2: per-row contribution (wave per row, captured diag) --------
__global__ void row_contrib(const float* __restrict__ diagArr,
                            const float* __restrict__ partials_row,
                            const float* __restrict__ colsum,
                            const int* __restrict__ counts,
                            const int* __restrict__ labels, float* __restrict__ blockSums) {
    const int lane = threadIdx.x & 63;
    const int wave = threadIdx.x >> 6;
    const int row = blockIdx.x * 4 + wave;

    // S_row: NSLICE partials in lanes 0..NSLICE-1 (zeros elsewhere)
    float sr = (lane < NSLICE) ? partials_row[(size_t)row * NSLICE + lane] : 0.0f;
#pragma unroll
    for (int off = 16; off > 0; off >>= 1) sr += __shfl_xor(sr, off, 64);

    __shared__ float sums[4];
    if (lane == 0) {
        const float diag = 2.0f * diagArr[row];        // temperature 0.5
        const int cnt = counts[labels[row]] - 1;       // equal-label count excl. self
        const float cntlog = (cnt > 0) ? __logf((float)cnt) : -INFINITY;
        const float S_col = colsum[row];
        const float lse_total = final_lse(sr, cntlog, diag) + final_lse(S_col, cntlog, diag);
        sums[wave] = 2.0f * diag - lse_total;
    }
    __syncthreads();
    if (threadIdx.x == 0)
        blockSums[blockIdx.x] = sums[0] + sums[1] + sums[2] + sums[3];
}

// ---------------- kernel 3: final deterministic reduce ----------------
__global__ void final_reduce(const float* __restrict__ blockSums, float* __restrict__ out) {
    __shared__ float red[256];
    float v = 0.0f;
    for (int i = threadIdx.x; i < N / 4; i += 256) v += blockSums[i];
    red[threadIdx.x] = v;
    __syncthreads();
    for (int st = 128; st > 0; st >>= 1) {
        if (threadIdx.x < st) red[threadIdx.x] += red[threadIdx.x + st];
        __syncthreads();
    }
    if (threadIdx.x == 0) out[0] = -red[0] / (float)N;
}

extern "C" void kernel_launch(void* const* d_in, const int* in_sizes, int n_in,
                              void* d_out, int out_size, void* d_ws, size_t ws_size,
                              hipStream_t stream) {
    const float* F = (const float*)d_in[0];
    const float* Imp = (const float*)d_in[1];
    const int* labels = (const int*)d_in[2];
    float* out = (float*)d_out;

    char* ws = (char*)d_ws;
    size_t off = 0;
    unsigned char* Fb8 = (unsigned char*)(ws + off); off += (size_t)N * D;    // 2 MB
    unsigned char* Ib8 = (unsigned char*)(ws + off); off += (size_t)N * D;    // 2 MB
    float* partials_row = (float*)(ws + off); off += (size_t)N * NSLICE * 4;  // 512 KB
    float* colsum = (float*)(ws + off); off += (size_t)N * 4;                 // 32 KB
    float* diagArr = (float*)(ws + off); off += (size_t)N * 4;                // 32 KB
    float* blockSums = (float*)(ws + off); off += (size_t)(N / 4) * 4;        // 8 KB
    int* counts = (int*)(ws + off);

    dim3 cgrid(N * D / 8 / 256, 2);  // y0: F conv (+hist), y1: Imp conv (+colsum zero)
    convert_fp8<<<cgrid, 256, 0, stream>>>(F, Imp, (unsigned int*)Fb8, (unsigned int*)Ib8,
                                           labels, counts, colsum);

    dim3 g(NRB, NSLICE);
    tile_pass<<<g, 256, 0, stream>>>(Fb8, Ib8, labels, partials_row, colsum, diagArr);

    row_contrib<<<N / 4, 256, 0, stream>>>(diagArr, partials_row, colsum, counts, labels, blockSums);
    final_reduce<<<1, 256, 0, stream>>>(blockSums, out);
}

// Round 22
// 57.251 us; speedup vs baseline: 1.0266x; 1.0266x over previous
//
#include <hip/hip_runtime.h>
#include <hip/hip_bf16.h>

#define N 8192
#define D 256
#define NSLICE 16
#define BM 256                          // rows per block (4 waves x 64 rows)
#define TROWS 4                         // row-tiles of 16 per wave
#define COLS_PER_SLICE (N / NSLICE)     // 512
#define NSTRIP (COLS_PER_SLICE / 16)    // 32 strips of 16 cols
#define NRB (N / BM)                    // 32 row blocks

#define CSHIFT 160.0f                   // fixed base-2 LSE shift
#define K2LOG2E 2.885390082f            // (1/T) * log2(e) = 2 * 1.44269504
#define LN2F 0.6931471805599453f

typedef __attribute__((ext_vector_type(4))) float f32x4;

__device__ inline float fast_exp2(float x) { return __builtin_amdgcn_exp2f(x); }
__device__ inline float fast_log2(float x) { return __builtin_amdgcn_logf(x); }

// pack 4 fp32 -> 4 fp8 e4m3 bytes (OCP on gfx950)
__device__ inline unsigned int pack_fp8x4(float a, float b, float c, float d) {
    unsigned int p = __builtin_amdgcn_cvt_pk_fp8_f32(a, b, 0, 0);    // bytes 0-1
    p = __builtin_amdgcn_cvt_pk_fp8_f32(c, d, (int)p, 1);            // bytes 2-3
    return p;
}

// ---------------- kernel 0: fp32 -> fp8 (fragment order) + diag + hist + zero ----------------
// y==0: F -> Fb8 fragment-order; y==1: Imp -> Ib8 fragment-order.
// y==2: per-block 8 rows of fp32 diag dot + zero colsum[8]; block x==0 also
//       computes the 14-bin ballot label histogram (counts).
__global__ void convert_fp8(const float* __restrict__ F, const float* __restrict__ Imp,
                            unsigned int* __restrict__ Fb8, unsigned int* __restrict__ Ib8,
                            const int* __restrict__ labels, int* __restrict__ counts,
                            float* __restrict__ diagArr, float* __restrict__ colsum) {
    const int tid = threadIdx.x;
    if (blockIdx.y < 2) {
        const int i = blockIdx.x * blockDim.x + tid;  // 8 bytes per thread
        const float* src = (blockIdx.y == 0) ? F : Imp;
        unsigned int* dst = (blockIdx.y == 0) ? Fb8 : Ib8;
        const int l = i & 63;
        const int ks = (i >> 6) & 7;
        const int g = i >> 9;
        const int row = g * 16 + (l & 15);
        const int k0 = ks * 32 + (l >> 4) * 8;
        const float* p = src + (size_t)row * D + k0;
        const float4 v0 = *reinterpret_cast<const float4*>(p);
        const float4 v1 = *reinterpret_cast<const float4*>(p + 4);
        dst[i * 2] = pack_fp8x4(v0.x, v0.y, v0.z, v0.w);
        dst[i * 2 + 1] = pack_fp8x4(v1.x, v1.y, v1.z, v1.w);
        return;
    }
    // y == 2: diag dots (8 rows/block), zero colsum, block 0 does the hist
    const int row = blockIdx.x * 8 + (tid >> 5);
    const int sl = tid & 31;                      // 32 lanes per row
    const float* fr = F + (size_t)row * D + sl * 8;
    const float* ir = Imp + (size_t)row * D + sl * 8;
    const float4 f0 = *reinterpret_cast<const float4*>(fr);
    const float4 f1 = *reinterpret_cast<const float4*>(fr + 4);
    const float4 i0 = *reinterpret_cast<const float4*>(ir);
    const float4 i1 = *reinterpret_cast<const float4*>(ir + 4);
    float dot = f0.x * i0.x + f0.y * i0.y + f0.z * i0.z + f0.w * i0.w +
                f1.x * i1.x + f1.y * i1.y + f1.z * i1.z + f1.w * i1.w;
#pragma unroll
    for (int off = 16; off > 0; off >>= 1) dot += __shfl_xor(dot, off, 64);  // within 32-group
    if (sl == 0) diagArr[row] = dot;
    if (tid < 8) colsum[blockIdx.x * 8 + tid] = 0.0f;

    if (blockIdx.x == 0) {  // ballot histogram, one block
        const int lane = tid & 63;
        const int wave = tid >> 6;
        int c = 0;
        for (int i = wave * 2048 + lane; i < wave * 2048 + 2048; i += 64) {
            const int lab = labels[i];
#pragma unroll
            for (int b = 0; b < 14; ++b) {
                unsigned long long m = __ballot(lab == b);
                if (lane == b) c += __popcll(m);
            }
        }
        __shared__ int wc[4][16];
        if (lane < 16) wc[wave][lane] = (lane < 14) ? c : 0;
        __syncthreads();
        if (tid < 16)
            counts[tid] = wc[0][tid] + wc[1][tid] + wc[2][tid] + wc[3][tid];
    }
}

// ---------------- kernel 1: free-running fp8 kernel, deferred-epilogue pipeline --------
// Best measured config (r20, 57.27us total). No B LDS staging, no main-loop
// barriers, two acc sets (strip st's exp2/VALU epilogue runs in the shadow of
// strip st+1's in-flight MFMA cluster), launch_bounds(256,2) — any tighter cap
// spills (r5/r10/r16/r18). NSLICE=16 -> grid 512 = exactly 2 blocks/CU, one
// dispatch round. Col-sums atomicAdd'ed into pre-zeroed global colsum.
// blockIdx.x: row block (256 rows), blockIdx.y: column slice (512 cols).
__launch_bounds__(256, 2)
__global__ void tile_pass(const unsigned char* __restrict__ Fb8,
                          const unsigned char* __restrict__ Ib8,
                          const int* __restrict__ labels,
                          float* __restrict__ partials_row,    // [N][NSLICE]
                          float* __restrict__ colsum) {        // [N], atomic
    __shared__ float colacc[4][COLS_PER_SLICE];   // 8KB, per-wave private
    __shared__ int labs[COLS_PER_SLICE];          // 2KB

    const int tid = threadIdx.x;
    const int lane = tid & 63;
    const int wave = tid >> 6;
    const int rb = blockIdx.x;
    const int row0 = rb * BM + wave * (16 * TROWS);
    const int rg0 = row0 >> 4;                    // A row-group index
    const int c0 = blockIdx.y * COLS_PER_SLICE;
    const int cg0 = c0 >> 4;                      // B col-group index
    const int lrow = lane & 15;
    const int kgrp = lane >> 4;

    for (int i = tid; i < COLS_PER_SLICE; i += 256) {
        labs[i] = labels[c0 + i];
        colacc[0][i] = 0.f; colacc[1][i] = 0.f; colacc[2][i] = 0.f; colacc[3][i] = 0.f;
    }

    // A fragments (fragment-ordered global): coalesced b64 per (t,ks)
    long afrag[TROWS][8];
#pragma unroll
    for (int t = 0; t < TROWS; ++t)
#pragma unroll
        for (int ks = 0; ks < 8; ++ks)
            afrag[t][ks] = *reinterpret_cast<const long*>(
                Fb8 + (size_t)(rg0 + t) * 4096 + ks * 512 + lane * 8);

    int labr[TROWS][4];
#pragma unroll
    for (int t = 0; t < TROWS; ++t) {
        const int base = row0 + t * 16 + kgrp * 4;
#pragma unroll
        for (int r = 0; r < 4; ++r) labr[t][r] = labels[base + r];
    }

    float s[TROWS][4];
#pragma unroll
    for (int t = 0; t < TROWS; ++t)
#pragma unroll
        for (int r = 0; r < 4; ++r) s[t][r] = 0.0f;

    __syncthreads();  // labs/colacc ready — the ONLY pre-epilogue barrier

#define LOADB(buf, st)                                                          \
    {                                                                           \
        const unsigned char* sb = Ib8 + (size_t)(cg0 + (st)) * 4096 + lane * 8; \
        _Pragma("unroll")                                                       \
        for (int ks = 0; ks < 8; ++ks)                                          \
            buf[ks] = *reinterpret_cast<const long*>(sb + ks * 512);            \
    }

#define MFMA_STRIP(acc, buf)                                                    \
    {                                                                           \
        _Pragma("unroll")                                                       \
        for (int t = 0; t < TROWS; ++t) acc[t] = f32x4{0.f, 0.f, 0.f, 0.f};     \
        _Pragma("unroll")                                                       \
        for (int ks = 0; ks < 8; ++ks)                                          \
            _Pragma("unroll")                                                   \
            for (int t = 0; t < TROWS; ++t)                                     \
                acc[t] = __builtin_amdgcn_mfma_f32_16x16x32_fp8_fp8(            \
                    afrag[t][ks], buf[ks], acc[t], 0, 0, 0);                    \
    }

#define EPI(acc, st)                                                            \
    {                                                                           \
        const int labc = labs[(st) * 16 + lrow];                                \
        float colpart = 0.0f;                                                   \
        _Pragma("unroll")                                                       \
        for (int t = 0; t < TROWS; ++t) {                                       \
            _Pragma("unroll")                                                   \
            for (int r = 0; r < 4; ++r) {                                       \
                float arg = __builtin_fmaf(acc[t][r], K2LOG2E, -CSHIFT);        \
                arg = (labr[t][r] == labc) ? -1000.0f : arg;                    \
                float e = fast_exp2(arg);                                       \
                s[t][r] += e;                                                   \
                colpart += e;                                                   \
            }                                                                   \
        }                                                                       \
        colpart += __shfl_xor(colpart, 16, 64);                                 \
        colpart += __shfl_xor(colpart, 32, 64);                                 \
        if (kgrp == 0) colacc[wave][(st) * 16 + lrow] += colpart;               \
    }

    long b0[8], b1[8];
    f32x4 acc0[TROWS], acc1[TROWS];

    LOADB(b0, 0);
    LOADB(b1, 1);
    MFMA_STRIP(acc0, b0);

#pragma unroll 1
    for (int st = 0; st < NSTRIP; st += 2) {
        if (st + 2 < NSTRIP) LOADB(b0, st + 2);
        MFMA_STRIP(acc1, b1);
        EPI(acc0, st);
        if (st + 3 < NSTRIP) LOADB(b1, st + 3);
        if (st + 2 < NSTRIP) MFMA_STRIP(acc0, b0);
        EPI(acc1, st + 1);
    }
#undef LOADB
#undef MFMA_STRIP
#undef EPI

    // row partials: sum the 16 lrow-lanes (disjoint column subsets)
#pragma unroll
    for (int off = 1; off < 16; off <<= 1) {
#pragma unroll
        for (int t = 0; t < TROWS; ++t)
#pragma unroll
            for (int r = 0; r < 4; ++r)
                s[t][r] += __shfl_xor(s[t][r], off, 64);
    }
    if (lrow == 0) {
#pragma unroll
        for (int t = 0; t < TROWS; ++t)
#pragma unroll
            for (int r = 0; r < 4; ++r) {
                const int grow = row0 + t * 16 + kgrp * 4 + r;
                partials_row[(size_t)grow * NSLICE + blockIdx.y] = s[t][r];
            }
    }

    __syncthreads();  // all colacc writes visible
    for (int i = tid; i < COLS_PER_SLICE; i += 256) {
        float v = colacc[0][i] + colacc[1][i] + colacc[2][i] + colacc[3][i];
        atomicAdd(&colsum[c0 + i], v);  // 32 blocks per address, pre-zeroed
    }
}

// exact lse over { S*2^CSHIFT (bulk), cnt*exp(0), exp(diag) }
__device__ inline float final_lse(float S, float cntlog, float diag) {
    float l1 = (S > 0.0f) ? (CSHIFT + fast_log2(S)) * LN2F : -INFINITY;
    float M = fmaxf(fmaxf(l1, cntlog), diag);  // M finite: diag always finite
    return M + __logf(__expf(l1 - M) + __expf(cntlog - M) + __expf(diag - M));
}

// ---------------- kernel 2: per-row contribution (wave per row, precomputed diag) ------
__global__ void row_contrib(const float* __restrict__ diagArr,
                            const float* __restrict__ partials_row,
                            const float* __restrict__ colsum,
                            const int* __restrict__ counts,
                            const int* __restrict__ labels, float* __restrict__ blockSums) {
    const int lane = threadIdx.x & 63;
    const int wave = threadIdx.x >> 6;
    const int row = blockIdx.x * 4 + wave;

    // S_row: NSLICE partials in lanes 0..NSLICE-1 (zeros elsewhere)
    float sr = (lane < NSLICE) ? partials_row[(size_t)row * NSLICE + lane] : 0.0f;
#pragma unroll
    for (int off = 16; off > 0; off >>= 1) sr += __shfl_xor(sr, off, 64);

    __shared__ float sums[4];
    if (lane == 0) {
        const float diag = 2.0f * diagArr[row];        // temperature 0.5
        const int cnt = counts[labels[row]] - 1;       // equal-label count excl. self
        const float cntlog = (cnt > 0) ? __logf((float)cnt) : -INFINITY;
        const float S_col = colsum[row];
        const float lse_total = final_lse(sr, cntlog, diag) + final_lse(S_col, cntlog, diag);
        sums[wave] = 2.0f * diag - lse_total;
    }
    __syncthreads();
    if (threadIdx.x == 0)
        blockSums[blockIdx.x] = sums[0] + sums[1] + sums[2] + sums[3];
}

// ---------------- kernel 3: final deterministic reduce ----------------
__global__ void final_reduce(const float* __restrict__ blockSums, float* __restrict__ out) {
    __shared__ float red[256];
    float v = 0.0f;
    for (int i = threadIdx.x; i < N / 4; i += 256) v += blockSums[i];
    red[threadIdx.x] = v;
    __syncthreads();
    for (int st = 128; st > 0; st >>= 1) {
        if (threadIdx.x < st) red[threadIdx.x] += red[threadIdx.x + st];
        __syncthreads();
    }
    if (threadIdx.x == 0) out[0] = -red[0] / (float)N;
}

extern "C" void kernel_launch(void* const* d_in, const int* in_sizes, int n_in,
                              void* d_out, int out_size, void* d_ws, size_t ws_size,
                              hipStream_t stream) {
    const float* F = (const float*)d_in[0];
    const float* Imp = (const float*)d_in[1];
    const int* labels = (const int*)d_in[2];
    float* out = (float*)d_out;

    char* ws = (char*)d_ws;
    size_t off = 0;
    unsigned char* Fb8 = (unsigned char*)(ws + off); off += (size_t)N * D;    // 2 MB
    unsigned char* Ib8 = (unsigned char*)(ws + off); off += (size_t)N * D;    // 2 MB
    float* partials_row = (float*)(ws + off); off += (size_t)N * NSLICE * 4;  // 512 KB
    float* colsum = (float*)(ws + off); off += (size_t)N * 4;                 // 32 KB
    float* diagArr = (float*)(ws + off); off += (size_t)N * 4;                // 32 KB
    float* blockSums = (float*)(ws + off); off += (size_t)(N / 4) * 4;        // 8 KB
    int* counts = (int*)(ws + off);

    dim3 cgrid(N * D / 8 / 256, 3);  // y0: F conv, y1: Imp conv, y2: diag+hist+zero
    convert_fp8<<<cgrid, 256, 0, stream>>>(F, Imp, (unsigned int*)Fb8, (unsigned int*)Ib8,
                                           labels, counts, diagArr, colsum);

    dim3 g(NRB, NSLICE);
    tile_pass<<<g, 256, 0, stream>>>(Fb8, Ib8, labels, partials_row, colsum);

    row_contrib<<<N / 4, 256, 0, stream>>>(diagArr, partials_row, colsum, counts, labels, blockSums);
    final_reduce<<<1, 256, 0, stream>>>(blockSums, out);
}